// Round 6
// baseline (2223.509 us; speedup 1.0000x reference)
//
#include <hip/hip_runtime.h>
#include <hip/hip_bf16.h>

namespace {

using bf16x8 = __attribute__((ext_vector_type(8))) short;
using f32x4  = __attribute__((ext_vector_type(4))) float;

constexpr int NL = 9, BB = 8192;
constexpr int G = 7;             // sequences per block (1 per wave)
constexpr int M1 = 49;           // token rows per state (7 seq x 7 tok)
constexpr int NT = 512;          // 8 waves

// LDS layout (bytes)
constexpr int OFF_F1 = 0;        // fp32 [49][64] swizzled (32B granule)
constexpr int OFF_F2 = 12544;    // fp32 [49][64]
constexpr int OFF_SQ = 25088;    // fp32 [49][64]
constexpr int OFF_QB = 37632;    // bf16 [98][64] swizzled (Q / ctx / ffn-hidden)
constexpr int OFF_KB = 50176;    // bf16 [98][64] swizzled (K)
constexpr int OFF_VT = 62720;    // bf16 V [64 d][128 kv] swizzled
constexpr int SMEM_TOTAL = 79104;    // <= 81920 -> 2 blocks/CU

__device__ __forceinline__ unsigned short f2bf(float f) {
  union { __hip_bfloat16 h; unsigned short s; } u;
  u.h = __float2bfloat16(f);
  return u.s;
}
__device__ __forceinline__ uint32_t pk2(float a, float b) {
  return (uint32_t)f2bf(a) | ((uint32_t)f2bf(b) << 16);
}
__device__ __forceinline__ int swzS(int r, int c) {   // fp32 [*][64]
  return r * 256 + ((((c >> 3) ^ (r & 7)) << 5) | ((c & 7) << 2));
}
__device__ __forceinline__ int swzB(int r, int c) {   // bf16 [*][64]
  return r * 128 + ((((c >> 3) ^ (r & 7)) << 4) | ((c & 7) << 1));
}
__device__ __forceinline__ int swzV(int d, int kv) {  // bf16 [64][128]
  return d * 256 + ((((kv >> 3) ^ (d & 7)) << 4) | ((kv & 7) << 1));
}
__device__ __forceinline__ int div7(int t) { return (t * 9363) >> 16; }  // t < 98

// state fp32 (swizzled) -> bf16x8 fragment: 8 consecutive k (k0 % 8 == 0)
__device__ __forceinline__ bf16x8 ldStateFrag(const char* base, int r, int k0) {
  const float4* p = (const float4*)(base + r * 256 + (((k0 >> 3) ^ (r & 7)) << 5));
  float4 x = p[0], y = p[1];
  union { bf16x8 v; uint32_t u[4]; } o;
  o.u[0] = pk2(x.x, x.y); o.u[1] = pk2(x.z, x.w);
  o.u[2] = pk2(y.x, y.y); o.u[3] = pk2(y.z, y.w);
  return o.v;
}
__device__ __forceinline__ bf16x8 ldBfFrag(const char* base, int r, int k0) {
  return *(const bf16x8*)(base + r * 128 + (((k0 >> 3) ^ (r & 7)) << 4));
}

// ---------------- compile-time B-fragment sources ----------------
enum : int { BS_F1 = 0, BS_F2, BS_SQ, BS_F1F2, BS_QB0, BS_QB49 };

template <int BS>
__device__ __forceinline__ bf16x8 bfrag(const char* smem, int r, int k0)
{
  if constexpr (BS == BS_F1) {
    return ldStateFrag(smem + OFF_F1, r > 48 ? 48 : r, k0);
  } else if constexpr (BS == BS_F2) {
    return ldStateFrag(smem + OFF_F2, r > 48 ? 48 : r, k0);
  } else if constexpr (BS == BS_SQ) {
    return ldStateFrag(smem + OFF_SQ, r > 48 ? 48 : r, k0);
  } else if constexpr (BS == BS_F1F2) {
    // SWIZZLE-KEY FIX: sF2 rows were stored with key (t2&7) at OFF_F2.
    // Reading row 49+t2 through OFF_F1 would use key ((49+t2)&7) != (t2&7)
    // (49 % 8 != 0) and permute the 8-col granules. Select base + local row
    // so the XOR key matches the store key.
    const int f2 = r >= 49;
    int rr = f2 ? r - 49 : r;
    rr = rr > 48 ? 48 : rr;
    return ldStateFrag(smem + (f2 ? OFF_F2 : OFF_F1), rr, k0);
  } else if constexpr (BS == BS_QB0) {
    return ldBfFrag(smem + OFF_QB, r > 97 ? 97 : r, k0);
  } else { // BS_QB49
    int rr = r > 48 ? 48 : r;
    return ldBfFrag(smem + OFF_QB, 49 + rr, k0);
  }
}

// ---------------- compile-time epilogues ----------------
enum : int { OM_QKV0 = 0, OM_QKV1, OM_QCA, OM_KVCA, OM_RESF0, OM_RESF1, OM_RESQ, OM_RELU };

// normal (swapped) tiles: lane owns token col, 4 consecutive out-features
template <int OM>
__device__ __forceinline__ void epi_n(char* smem, int nt, int tok, int gI, f32x4 a)
{
  if constexpr (OM == OM_RESF0 || OM == OM_RESF1 || OM == OM_RESQ) {
    constexpr int off = (OM == OM_RESF0) ? OFF_F1 : (OM == OM_RESF1) ? OFF_F2 : OFF_SQ;
    const int c0 = nt * 16 + gI * 4;
    float4* p = (float4*)(smem + off + tok * 256 + (((c0 >> 3) ^ (tok & 7)) << 5) + ((c0 & 7) << 2));
    float4 v = *p;
    v.x += a[0]; v.y += a[1]; v.z += a[2]; v.w += a[3];
    *p = v;
  } else if constexpr (OM == OM_RELU) {
    *(uint2*)(smem + OFF_QB + swzB(tok, nt * 16 + gI * 4)) =
        make_uint2(pk2(fmaxf(a[0], 0.f), fmaxf(a[1], 0.f)),
                   pk2(fmaxf(a[2], 0.f), fmaxf(a[3], 0.f)));
  } else {
    const uint2 val = make_uint2(pk2(a[0], a[1]), pk2(a[2], a[3]));
    if constexpr (OM == OM_QKV0 || OM == OM_QKV1) {
      constexpr int RO = (OM == OM_QKV1) ? 49 : 0;
      if (nt < 4) *(uint2*)(smem + OFF_QB + swzB(RO + tok, nt * 16 + gI * 4)) = val;
      else        *(uint2*)(smem + OFF_KB + swzB(RO + tok, (nt - 4) * 16 + gI * 4)) = val;
    } else if constexpr (OM == OM_QCA) {
      *(uint2*)(smem + OFF_QB + swzB(tok, nt * 16 + gI * 4)) = val;
    } else { // OM_KVCA : K rows interleaved [f1(7);f2(7)] per seq
      const int f2 = tok >= 49;
      const int t2 = f2 ? tok - 49 : tok;
      const int g = div7(t2);
      const int row = 14 * g + (t2 - 7 * g) + (f2 ? 7 : 0);
      *(uint2*)(smem + OFF_KB + swzB(row, nt * 16 + gI * 4)) = val;
    }
  }
}

// V tiles: lane owns feature d, 4 token rows -> scatter into vt[d][slot]
template <int OM>
__device__ __forceinline__ void epi_v(char* smem, int d, int tokbase, f32x4 a)
{
#pragma unroll
  for (int jj = 0; jj < 4; ++jj) {
    const int tok = tokbase + jj;
    if constexpr (OM == OM_QKV0 || OM == OM_QKV1) {
      if (tok < 49) {
        const int g = div7(tok);
        const int slot = ((OM == OM_QKV1) ? 56 : 0) + 8 * g + (tok - 7 * g);
        *(short*)(smem + OFF_VT + swzV(d, slot)) = (short)f2bf(a[jj]);
      }
    } else { // OM_KVCA : 16 slots/seq, f1 j..j+6, f2 +7
      if (tok < 98) {
        const int f2 = tok >= 49;
        const int t2 = f2 ? tok - 49 : tok;
        const int g = div7(t2);
        const int slot = 16 * g + (t2 - 7 * g) + (f2 ? 7 : 0);
        *(short*)(smem + OFF_VT + swzV(d, slot)) = (short)f2bf(a[jj]);
      }
    }
  }
}

// ---------------- GEMM: no functors, all modes compile-time ----------------
// Normal tiles (nt<VNT): D = W x state^T ; V tiles: D = state x W^T.
template <int MTI, int MV, int NTOT, int KF, int WMG, int WNG, int VNT,
          int BS, int OM, int NBOFF, int VBOFF, int LDK, bool WS>
__device__ __forceinline__ void gemm(char* smem, const short* __restrict__ wbf,
                                     const float* __restrict__ wf,
                                     const float* __restrict__ bias,
                                     int wid, int lane)
{
  const int wm = wid / WNG, wn = wid % WNG;
  const int q = lane & 15, gI = lane >> 4;
  constexpr int MPW = (MTI + WMG - 1) / WMG;
  constexpr int NPW = NTOT / WNG;
  bf16x8 bfr[MPW][KF];
#pragma unroll
  for (int i = 0; i < MPW; ++i) {
    const int mt = wm * MPW + i;
    if (mt < MTI) {
#pragma unroll
      for (int kf = 0; kf < KF; ++kf)
        bfr[i][kf] = bfrag<BS>(smem, mt * 16 + q, kf * 32 + gI * 8);
    }
  }
#pragma unroll
  for (int j = 0; j < NPW; ++j) {
    const int nt = wn * NPW + j;
    bf16x8 afr[KF];
#pragma unroll
    for (int kf = 0; kf < KF; ++kf) {
      const int k0 = kf * 32 + gI * 8;
      if constexpr (WS) {
        afr[kf] = *(const bf16x8*)(wbf + (nt * 16 + q) * LDK + k0);
      } else {
        const float* wp = wf + (nt * 16 + q) * LDK + k0;
        float4 x = *(const float4*)wp, y = *(const float4*)(wp + 4);
        union { bf16x8 v; uint32_t u[4]; } o;
        o.u[0] = pk2(x.x, x.y); o.u[1] = pk2(x.z, x.w);
        o.u[2] = pk2(y.x, y.y); o.u[3] = pk2(y.z, y.w);
        afr[kf] = o.v;
      }
    }
    if (nt < VNT) {
      const float4 b4 = *(const float4*)(bias + NBOFF + nt * 16 + gI * 4);
#pragma unroll
      for (int i = 0; i < MPW; ++i) {
        const int mt = wm * MPW + i;
        if (mt < MTI) {
          f32x4 acc = { b4.x, b4.y, b4.z, b4.w };
#pragma unroll
          for (int kf = 0; kf < KF; ++kf)
            acc = __builtin_amdgcn_mfma_f32_16x16x32_bf16(afr[kf], bfr[i][kf], acc, 0, 0, 0);
          const int tok = mt * 16 + q;
          if (tok < MV) epi_n<OM>(smem, nt, tok, gI, acc);
        }
      }
    } else {
      const float bv = bias[VBOFF + (nt - VNT) * 16 + q];
#pragma unroll
      for (int i = 0; i < MPW; ++i) {
        const int mt = wm * MPW + i;
        if (mt < MTI) {
          f32x4 acc = { bv, bv, bv, bv };
#pragma unroll
          for (int kf = 0; kf < KF; ++kf)
            acc = __builtin_amdgcn_mfma_f32_16x16x32_bf16(bfr[i][kf], afr[kf], acc, 0, 0, 0);
          epi_v<OM>(smem, (nt - VNT) * 16 + q, mt * 16 + gI * 4, acc);
        }
      }
    }
  }
}

// ---------------- attention: one (seq, sa/ca) unit per call ----------------
__device__ __forceinline__ void attn_unit(char* smem, int qrow0, int krow0,
                                          int cb, int kvl, int lane)
{
  const int q = lane & 15, gI = lane >> 4;
  char* qb = smem + OFF_QB;
  const char* kb = smem + OFF_KB;
  const char* vt = smem + OFF_VT;
#pragma unroll
  for (int h = 0; h < 4; ++h) {
    bf16x8 kfrag = {}, qfrag = {};
    if (gI < 2) {
      const int qr = qrow0 + (q < 7 ? q : 6);
      qfrag = ldBfFrag(qb, qr, h * 16 + gI * 8);
      const int kr = krow0 + (q < kvl ? q : kvl - 1);
      kfrag = ldBfFrag(kb, kr, h * 16 + gI * 8);
    }
    f32x4 s = { 0.f, 0.f, 0.f, 0.f };
    s = __builtin_amdgcn_mfma_f32_16x16x32_bf16(kfrag, qfrag, s, 0, 0, 0);

    float e0, e1, e2, e3; float sum;
    {
      const float t0 = fminf(s[0] * 0.36067376f, 60.f);   // *0.25 * log2(e)
      const float t1 = fminf(s[1] * 0.36067376f, 60.f);
      const float t2 = fminf(s[2] * 0.36067376f, 60.f);
      const float t3 = fminf(s[3] * 0.36067376f, 60.f);
      e0 = (gI * 4 + 0 < kvl) ? exp2f(t0) : 0.f;
      e1 = (gI * 4 + 1 < kvl) ? exp2f(t1) : 0.f;
      e2 = (gI * 4 + 2 < kvl) ? exp2f(t2) : 0.f;
      e3 = (gI * 4 + 3 < kvl) ? exp2f(t3) : 0.f;
      sum = e0 + e1 + e2 + e3;
    }
    sum += __shfl_xor(sum, 16);
    sum += __shfl_xor(sum, 32);
    const float inv = __builtin_amdgcn_rcpf(sum);

    union { bf16x8 v; uint32_t u[4]; } pb;
    pb.u[0] = pk2(e0 * inv, e1 * inv);
    pb.u[1] = pk2(e2 * inv, e3 * inv);
    pb.u[2] = 0; pb.u[3] = 0;

    const int d = h * 16 + q;
    const uint2 vv = *(const uint2*)(vt + swzV(d, cb + gI * 4));
    union { bf16x8 v; uint32_t u[4]; } va;
    va.u[0] = vv.x; va.u[1] = vv.y; va.u[2] = 0; va.u[3] = 0;

    f32x4 o = { 0.f, 0.f, 0.f, 0.f };
    o = __builtin_amdgcn_mfma_f32_16x16x32_bf16(va.v, pb.v, o, 0, 0, 0);

    if (q < 7) {
      *(uint2*)(qb + swzB(qrow0 + q, h * 16 + gI * 4)) =
          make_uint2(pk2(o[0], o[1]), pk2(o[2], o[3]));
    }
  }
}

template <bool WS>
__global__ __launch_bounds__(NT, 4) void pose_kernel(
    const float* __restrict__ feature1, const float* __restrict__ feature2,
    const float* __restrict__ sa1_win, const float* __restrict__ sa1_bin,
    const float* __restrict__ sa1_wout, const float* __restrict__ sa1_bout,
    const float* __restrict__ sa2_win, const float* __restrict__ sa2_bin,
    const float* __restrict__ sa2_wout, const float* __restrict__ sa2_bout,
    const float* __restrict__ ca_win, const float* __restrict__ ca_bin,
    const float* __restrict__ ca_wout, const float* __restrict__ ca_bout,
    const float* __restrict__ ff_w1, const float* __restrict__ ff_b1,
    const float* __restrict__ ff_w2, const float* __restrict__ ff_b2,
    const float* __restrict__ query_embed,
    const float* __restrict__ fc_rot_w, const float* __restrict__ fc_rot_b,
    const float* __restrict__ fc_trans_w, const float* __restrict__ fc_trans_b,
    const short* __restrict__ wbf, float* __restrict__ out)
{
  extern __shared__ char smem[];
  const int t = threadIdx.x;
  const int wid = t >> 6, lane = t & 63;
  const int bi = blockIdx.y;
  const int b0 = blockIdx.x * G;

  // zero-init V buffer (pad slots must be finite for MFMA)
  {
    const uint4 z = { 0, 0, 0, 0 };
    for (int i = t; i < 1024; i += NT) ((uint4*)(smem + OFF_VT))[i] = z;
  }
  // load per-sequence state (coalesced) into swizzled fp32 tiles
  {
    const float* f1p = feature1 + (size_t)b0 * 448;
    const float* f2p = feature2 + (size_t)b0 * 448;
    const float* qe  = query_embed + (size_t)bi * 448;
    const int lim = (BB - b0) * 448;   // guard for the last (partial) block
    for (int idx = t; idx < M1 * 64; idx += NT) {
      const int r = idx >> 6, c = idx & 63;
      const int s = r - div7(r) * 7;
      const bool ok = idx < lim;
      *(float*)(smem + OFF_F1 + swzS(r, c)) = ok ? f1p[idx] : 0.f;
      *(float*)(smem + OFF_F2 + swzS(r, c)) = ok ? f2p[idx] : 0.f;
      *(float*)(smem + OFF_SQ + swzS(r, c)) = qe[s * 64 + c];
    }
  }
  __syncthreads();

  for (int li = 0; li < NL; ++li) {
    const int wo = bi * NL + li;

    // P1: QKV for f1 and f2 (disjoint outputs, one barrier)
    gemm<4, 49, 12, 2, 2, 4, 8, BS_F1, OM_QKV0, 0, 128, 64, WS>(
        smem, wbf + wo * 12288, sa1_win + wo * 12288, sa1_bin + wo * 192, wid, lane);
    gemm<4, 49, 12, 2, 2, 4, 8, BS_F2, OM_QKV1, 0, 128, 64, WS>(
        smem, wbf + 221184 + wo * 12288, sa2_win + wo * 12288, sa2_bin + wo * 192, wid, lane);
    __syncthreads();

    // P2: attention f1 + f2 (14 units over 8 waves)
    {
      const int u = wid;                       // 0..7
      const int sa = u >= 7, g = u - 7 * sa;
      attn_unit(smem, 49 * sa + 7 * g, 49 * sa + 7 * g, 56 * sa + 8 * g, 7, lane);
      const int u2 = wid + 8;                  // 8..15
      if (u2 < 14) {
        const int g2 = u2 - 7;
        attn_unit(smem, 49 + 7 * g2, 49 + 7 * g2, 56 + 8 * g2, 7, lane);
      }
    }
    __syncthreads();

    // P3: out-proj f1 + f2 (residual RMW)
    gemm<4, 49, 4, 2, 2, 4, 99, BS_QB0, OM_RESF0, 0, 0, 64, WS>(
        smem, wbf + 663552 + wo * 4096, sa1_wout + wo * 4096, sa1_bout + wo * 64, wid, lane);
    gemm<4, 49, 4, 2, 2, 4, 99, BS_QB49, OM_RESF1, 0, 0, 64, WS>(
        smem, wbf + 737280 + wo * 4096, sa2_wout + wo * 4096, sa2_bout + wo * 64, wid, lane);
    __syncthreads();

    // P4: CA q-proj + merged kv-proj (f1,f2 share ca weights)
    gemm<4, 49, 4, 2, 2, 4, 99, BS_SQ, OM_QCA, 0, 0, 64, WS>(
        smem, wbf + 442368 + wo * 12288, ca_win + wo * 12288, ca_bin + wo * 192, wid, lane);
    gemm<7, 98, 8, 2, 2, 4, 4, BS_F1F2, OM_KVCA, 64, 128, 64, WS>(
        smem, wbf + 442368 + wo * 12288 + 4096, ca_win + wo * 12288 + 4096,
        ca_bin + wo * 192, wid, lane);
    __syncthreads();

    // P5: attention CA (7 units)
    if (wid < 7)
      attn_unit(smem, 7 * wid, 14 * wid, 16 * wid, 14, lane);
    __syncthreads();

    // P6: CA out-proj (RMW sQ)
    gemm<4, 49, 4, 2, 2, 4, 99, BS_QB0, OM_RESQ, 0, 0, 64, WS>(
        smem, wbf + 811008 + wo * 4096, ca_wout + wo * 4096, ca_bout + wo * 64, wid, lane);
    __syncthreads();

    // P7: FFN-1 (relu -> qb cols 0..31)
    gemm<4, 49, 2, 2, 4, 2, 99, BS_SQ, OM_RELU, 0, 0, 64, WS>(
        smem, wbf + 884736 + wo * 2048, ff_w1 + wo * 2048, ff_b1 + wo * 32, wid, lane);
    __syncthreads();

    // P8: FFN-2 (RMW sQ)
    gemm<4, 49, 4, 1, 2, 4, 99, BS_QB0, OM_RESQ, 0, 0, 32, WS>(
        smem, wbf + 921600 + wo * 2048, ff_w2 + wo * 2048, ff_b2 + wo * 64, wid, lane);
    __syncthreads();
  }

  // ---------- pose head ----------
  float* cs = (float*)(smem + OFF_QB);   // [7][64] fp32 scratch
  if (t < G * 64) {
    const int g = t >> 6, c = t & 63;
    float a = 0.f;
#pragma unroll
    for (int s = 0; s < 7; ++s) a += *(const float*)(smem + OFF_SQ + swzS(g * 7 + s, c));
    cs[t] = a;
  }
  __syncthreads();
  const int ncols = bi ? 3 : 4;
  if (t < G * ncols) {
    const int g = t / ncols, cc = t - g * ncols;
    if (b0 + g < BB) {
      const float* wv = bi ? (fc_trans_w + cc * 64) : (fc_rot_w + cc * 64);
      float acc = 0.f;
#pragma unroll
      for (int k = 0; k < 64; ++k) acc += cs[g * 64 + k] * wv[k];
      const float bb = bi ? fc_trans_b[cc] : fc_rot_b[cc];
      out[(size_t)(b0 + g) * 7 + (bi ? 4 : 0) + cc] = acc * (1.f / 7.f) + bb;
    }
  }
}

// Convert all weight matrices fp32 -> bf16 into workspace (once per call).
__global__ void prep_kernel(const float* __restrict__ a0, const float* __restrict__ a1,
                            const float* __restrict__ a2, const float* __restrict__ a3,
                            const float* __restrict__ a4, const float* __restrict__ a5,
                            const float* __restrict__ a6, const float* __restrict__ a7,
                            short* __restrict__ dst)
{
  for (int i = blockIdx.x * blockDim.x + threadIdx.x; i < 958464;
       i += gridDim.x * blockDim.x) {
    const float* s; int j;
    if      (i < 221184) { s = a0; j = i; }
    else if (i < 442368) { s = a1; j = i - 221184; }
    else if (i < 663552) { s = a2; j = i - 442368; }
    else if (i < 737280) { s = a3; j = i - 663552; }
    else if (i < 811008) { s = a4; j = i - 737280; }
    else if (i < 884736) { s = a5; j = i - 811008; }
    else if (i < 921600) { s = a6; j = i - 884736; }
    else                 { s = a7; j = i - 921600; }
    dst[i] = (short)f2bf(s[j]);
  }
}

} // namespace

extern "C" void kernel_launch(void* const* d_in, const int* in_sizes, int n_in,
                              void* d_out, int out_size, void* d_ws, size_t ws_size,
                              hipStream_t stream)
{
  const float* feature1    = (const float*)d_in[0];
  const float* feature2    = (const float*)d_in[1];
  const float* sa1_win     = (const float*)d_in[2];
  const float* sa1_bin     = (const float*)d_in[3];
  const float* sa1_wout    = (const float*)d_in[4];
  const float* sa1_bout    = (const float*)d_in[5];
  const float* sa2_win     = (const float*)d_in[6];
  const float* sa2_bin     = (const float*)d_in[7];
  const float* sa2_wout    = (const float*)d_in[8];
  const float* sa2_bout    = (const float*)d_in[9];
  const float* ca_win      = (const float*)d_in[10];
  const float* ca_bin      = (const float*)d_in[11];
  const float* ca_wout     = (const float*)d_in[12];
  const float* ca_bout     = (const float*)d_in[13];
  const float* ff_w1       = (const float*)d_in[14];
  const float* ff_b1       = (const float*)d_in[15];
  const float* ff_w2       = (const float*)d_in[16];
  const float* ff_b2       = (const float*)d_in[17];
  const float* query_embed = (const float*)d_in[18];
  const float* fc_rot_w    = (const float*)d_in[19];
  const float* fc_rot_b    = (const float*)d_in[20];
  const float* fc_trans_w  = (const float*)d_in[21];
  const float* fc_trans_b  = (const float*)d_in[22];

  const bool ws_ok = (d_ws != nullptr) && (ws_size >= (size_t)958464 * 2);
  dim3 grid((BB + G - 1) / G, 2);

  if (ws_ok) {
    prep_kernel<<<dim3(936), 512, 0, stream>>>(sa1_win, sa2_win, ca_win,
                                               sa1_wout, sa2_wout, ca_wout,
                                               ff_w1, ff_w2, (short*)d_ws);
    hipFuncSetAttribute(reinterpret_cast<const void*>(&pose_kernel<true>),
                        hipFuncAttributeMaxDynamicSharedMemorySize, SMEM_TOTAL);
    pose_kernel<true><<<grid, NT, SMEM_TOTAL, stream>>>(
        feature1, feature2,
        sa1_win, sa1_bin, sa1_wout, sa1_bout,
        sa2_win, sa2_bin, sa2_wout, sa2_bout,
        ca_win, ca_bin, ca_wout, ca_bout,
        ff_w1, ff_b1, ff_w2, ff_b2,
        query_embed, fc_rot_w, fc_rot_b, fc_trans_w, fc_trans_b,
        (const short*)d_ws, (float*)d_out);
  } else {
    hipFuncSetAttribute(reinterpret_cast<const void*>(&pose_kernel<false>),
                        hipFuncAttributeMaxDynamicSharedMemorySize, SMEM_TOTAL);
    pose_kernel<false><<<grid, NT, SMEM_TOTAL, stream>>>(
        feature1, feature2,
        sa1_win, sa1_bin, sa1_wout, sa1_bout,
        sa2_win, sa2_bin, sa2_wout, sa2_bout,
        ca_win, ca_bin, ca_wout, ca_bout,
        ff_w1, ff_b1, ff_w2, ff_b2,
        query_embed, fc_rot_w, fc_rot_b, fc_trans_w, fc_trans_b,
        (const short*)d_ws, (float*)d_out);
  }
}

// Round 7
// 2202.169 us; speedup vs baseline: 1.0097x; 1.0097x over previous
//
#include <hip/hip_runtime.h>
#include <hip/hip_bf16.h>

namespace {

using bf16x8 = __attribute__((ext_vector_type(8))) short;
using f32x4  = __attribute__((ext_vector_type(4))) float;

constexpr int NL = 9, BB = 8192;
constexpr int G = 7;             // sequences per block (1 per wave)
constexpr int M1 = 49;           // token rows per state (7 seq x 7 tok)
constexpr int NT = 512;          // 8 waves

// LDS layout (bytes)
constexpr int OFF_F1 = 0;        // fp32 [49][64] swizzled (32B granule)
constexpr int OFF_F2 = 12544;    // fp32 [49][64]
constexpr int OFF_SQ = 25088;    // fp32 [49][64]
constexpr int OFF_QB = 37632;    // bf16 [98][64] swizzled (Q / ctx / ffn-hidden)
constexpr int OFF_KB = 50176;    // bf16 [98][64] swizzled (K)
constexpr int OFF_VT = 62720;    // bf16 V [64 d][128 kv] swizzled
constexpr int SMEM_TOTAL = 79104;    // <= 81920 -> 2 blocks/CU

__device__ __forceinline__ unsigned short f2bf(float f) {
  union { __hip_bfloat16 h; unsigned short s; } u;
  u.h = __float2bfloat16(f);
  return u.s;
}
__device__ __forceinline__ uint32_t pk2(float a, float b) {
  return (uint32_t)f2bf(a) | ((uint32_t)f2bf(b) << 16);
}
__device__ __forceinline__ int swzS(int r, int c) {   // fp32 [*][64]
  return r * 256 + ((((c >> 3) ^ (r & 7)) << 5) | ((c & 7) << 2));
}
__device__ __forceinline__ int swzB(int r, int c) {   // bf16 [*][64]
  return r * 128 + ((((c >> 3) ^ (r & 7)) << 4) | ((c & 7) << 1));
}
__device__ __forceinline__ int swzV(int d, int kv) {  // bf16 [64][128]
  return d * 256 + ((((kv >> 3) ^ (d & 7)) << 4) | ((kv & 7) << 1));
}
__device__ __forceinline__ int div7(int t) { return (t * 9363) >> 16; }  // t < 98

// state fp32 (swizzled) -> bf16x8 fragment: 8 consecutive k (k0 % 8 == 0)
__device__ __forceinline__ bf16x8 ldStateFrag(const char* base, int r, int k0) {
  const float4* p = (const float4*)(base + r * 256 + (((k0 >> 3) ^ (r & 7)) << 5));
  float4 x = p[0], y = p[1];
  union { bf16x8 v; uint32_t u[4]; } o;
  o.u[0] = pk2(x.x, x.y); o.u[1] = pk2(x.z, x.w);
  o.u[2] = pk2(y.x, y.y); o.u[3] = pk2(y.z, y.w);
  return o.v;
}
__device__ __forceinline__ bf16x8 ldBfFrag(const char* base, int r, int k0) {
  return *(const bf16x8*)(base + r * 128 + (((k0 >> 3) ^ (r & 7)) << 4));
}

// ---------------- compile-time B-fragment sources ----------------
enum : int { BS_F1 = 0, BS_F2, BS_SQ, BS_F1F2, BS_QB0, BS_QB49 };

template <int BS>
__device__ __forceinline__ bf16x8 bfrag(const char* smem, int r, int k0)
{
  if constexpr (BS == BS_F1) {
    return ldStateFrag(smem + OFF_F1, r > 48 ? 48 : r, k0);
  } else if constexpr (BS == BS_F2) {
    return ldStateFrag(smem + OFF_F2, r > 48 ? 48 : r, k0);
  } else if constexpr (BS == BS_SQ) {
    return ldStateFrag(smem + OFF_SQ, r > 48 ? 48 : r, k0);
  } else if constexpr (BS == BS_F1F2) {
    // Swizzle-key match: F2 rows were stored with key (t2&7) at OFF_F2.
    const int f2 = r >= 49;
    int rr = f2 ? r - 49 : r;
    rr = rr > 48 ? 48 : rr;
    return ldStateFrag(smem + (f2 ? OFF_F2 : OFF_F1), rr, k0);
  } else if constexpr (BS == BS_QB0) {
    return ldBfFrag(smem + OFF_QB, r > 97 ? 97 : r, k0);
  } else { // BS_QB49
    int rr = r > 48 ? 48 : r;
    return ldBfFrag(smem + OFF_QB, 49 + rr, k0);
  }
}

// ---------------- compile-time epilogues ----------------
enum : int { OM_QKV0 = 0, OM_QKV1, OM_QCA, OM_KVCA, OM_RESF0, OM_RESF1, OM_RESQ, OM_RELU };

// normal (swapped) tiles: lane owns token col, 4 consecutive out-features
template <int OM>
__device__ __forceinline__ void epi_n(char* smem, int nt, int tok, int gI, f32x4 a)
{
  if constexpr (OM == OM_RESF0 || OM == OM_RESF1 || OM == OM_RESQ) {
    constexpr int off = (OM == OM_RESF0) ? OFF_F1 : (OM == OM_RESF1) ? OFF_F2 : OFF_SQ;
    const int c0 = nt * 16 + gI * 4;
    float4* p = (float4*)(smem + off + tok * 256 + (((c0 >> 3) ^ (tok & 7)) << 5) + ((c0 & 7) << 2));
    float4 v = *p;
    v.x += a[0]; v.y += a[1]; v.z += a[2]; v.w += a[3];
    *p = v;
  } else if constexpr (OM == OM_RELU) {
    *(uint2*)(smem + OFF_QB + swzB(tok, nt * 16 + gI * 4)) =
        make_uint2(pk2(fmaxf(a[0], 0.f), fmaxf(a[1], 0.f)),
                   pk2(fmaxf(a[2], 0.f), fmaxf(a[3], 0.f)));
  } else {
    const uint2 val = make_uint2(pk2(a[0], a[1]), pk2(a[2], a[3]));
    if constexpr (OM == OM_QKV0 || OM == OM_QKV1) {
      constexpr int RO = (OM == OM_QKV1) ? 49 : 0;
      if (nt < 4) *(uint2*)(smem + OFF_QB + swzB(RO + tok, nt * 16 + gI * 4)) = val;
      else        *(uint2*)(smem + OFF_KB + swzB(RO + tok, (nt - 4) * 16 + gI * 4)) = val;
    } else if constexpr (OM == OM_QCA) {
      *(uint2*)(smem + OFF_QB + swzB(tok, nt * 16 + gI * 4)) = val;
    } else { // OM_KVCA : K rows interleaved [f1(7);f2(7)] per seq
      const int f2 = tok >= 49;
      const int t2 = f2 ? tok - 49 : tok;
      const int g = div7(t2);
      const int row = 14 * g + (t2 - 7 * g) + (f2 ? 7 : 0);
      *(uint2*)(smem + OFF_KB + swzB(row, nt * 16 + gI * 4)) = val;
    }
  }
}

// V tiles: lane owns feature d, 4 token rows -> scatter into vt[d][slot]
template <int OM>
__device__ __forceinline__ void epi_v(char* smem, int d, int tokbase, f32x4 a)
{
#pragma unroll
  for (int jj = 0; jj < 4; ++jj) {
    const int tok = tokbase + jj;
    if constexpr (OM == OM_QKV0 || OM == OM_QKV1) {
      if (tok < 49) {
        const int g = div7(tok);
        const int slot = ((OM == OM_QKV1) ? 56 : 0) + 8 * g + (tok - 7 * g);
        *(short*)(smem + OFF_VT + swzV(d, slot)) = (short)f2bf(a[jj]);
      }
    } else { // OM_KVCA : 16 slots/seq, f1 j..j+6, f2 +7
      if (tok < 98) {
        const int f2 = tok >= 49;
        const int t2 = f2 ? tok - 49 : tok;
        const int g = div7(t2);
        const int slot = 16 * g + (t2 - 7 * g) + (f2 ? 7 : 0);
        *(short*)(smem + OFF_VT + swzV(d, slot)) = (short)f2bf(a[jj]);
      }
    }
  }
}

// ---------------- GEMM: no functors, all modes compile-time ----------------
// Normal tiles (nt<VNT): D = W x state^T ; V tiles: D = state x W^T.
template <int MTI, int MV, int NTOT, int KF, int WMG, int WNG, int VNT,
          int BS, int OM, int NBOFF, int VBOFF, int LDK, bool WS>
__device__ __forceinline__ void gemm(char* smem, const short* __restrict__ wbf,
                                     const float* __restrict__ wf,
                                     const float* __restrict__ bias,
                                     int wid, int lane)
{
  const int wm = wid / WNG, wn = wid % WNG;
  const int q = lane & 15, gI = lane >> 4;
  constexpr int MPW = (MTI + WMG - 1) / WMG;
  constexpr int NPW = NTOT / WNG;
  bf16x8 bfr[MPW][KF];
#pragma unroll
  for (int i = 0; i < MPW; ++i) {
    const int mt = wm * MPW + i;
    if (mt < MTI) {
#pragma unroll
      for (int kf = 0; kf < KF; ++kf)
        bfr[i][kf] = bfrag<BS>(smem, mt * 16 + q, kf * 32 + gI * 8);
    }
  }
#pragma unroll
  for (int j = 0; j < NPW; ++j) {
    const int nt = wn * NPW + j;
    bf16x8 afr[KF];
#pragma unroll
    for (int kf = 0; kf < KF; ++kf) {
      const int k0 = kf * 32 + gI * 8;
      if constexpr (WS) {
        afr[kf] = *(const bf16x8*)(wbf + (nt * 16 + q) * LDK + k0);
      } else {
        const float* wp = wf + (nt * 16 + q) * LDK + k0;
        float4 x = *(const float4*)wp, y = *(const float4*)(wp + 4);
        union { bf16x8 v; uint32_t u[4]; } o;
        o.u[0] = pk2(x.x, x.y); o.u[1] = pk2(x.z, x.w);
        o.u[2] = pk2(y.x, y.y); o.u[3] = pk2(y.z, y.w);
        afr[kf] = o.v;
      }
    }
    if (nt < VNT) {
      const float4 b4 = *(const float4*)(bias + NBOFF + nt * 16 + gI * 4);
#pragma unroll
      for (int i = 0; i < MPW; ++i) {
        const int mt = wm * MPW + i;
        if (mt < MTI) {
          f32x4 acc = { b4.x, b4.y, b4.z, b4.w };
#pragma unroll
          for (int kf = 0; kf < KF; ++kf)
            acc = __builtin_amdgcn_mfma_f32_16x16x32_bf16(afr[kf], bfr[i][kf], acc, 0, 0, 0);
          const int tok = mt * 16 + q;
          if (tok < MV) epi_n<OM>(smem, nt, tok, gI, acc);
        }
      }
    } else {
      const float bv = bias[VBOFF + (nt - VNT) * 16 + q];
#pragma unroll
      for (int i = 0; i < MPW; ++i) {
        const int mt = wm * MPW + i;
        if (mt < MTI) {
          f32x4 acc = { bv, bv, bv, bv };
#pragma unroll
          for (int kf = 0; kf < KF; ++kf)
            acc = __builtin_amdgcn_mfma_f32_16x16x32_bf16(bfr[i][kf], afr[kf], acc, 0, 0, 0);
          epi_v<OM>(smem, (nt - VNT) * 16 + q, mt * 16 + gI * 4, acc);
        }
      }
    }
  }
}

// ---------------- attention: one (seq, sa/ca) unit per call ----------------
__device__ __forceinline__ void attn_unit(char* smem, int qrow0, int krow0,
                                          int cb, int kvl, int lane)
{
  const int q = lane & 15, gI = lane >> 4;
  char* qb = smem + OFF_QB;
  const char* kb = smem + OFF_KB;
  const char* vt = smem + OFF_VT;
#pragma unroll
  for (int h = 0; h < 4; ++h) {
    bf16x8 kfrag = {}, qfrag = {};
    if (gI < 2) {
      const int qr = qrow0 + (q < 7 ? q : 6);
      qfrag = ldBfFrag(qb, qr, h * 16 + gI * 8);
      const int kr = krow0 + (q < kvl ? q : kvl - 1);
      kfrag = ldBfFrag(kb, kr, h * 16 + gI * 8);
    }
    f32x4 s = { 0.f, 0.f, 0.f, 0.f };
    s = __builtin_amdgcn_mfma_f32_16x16x32_bf16(kfrag, qfrag, s, 0, 0, 0);

    float e0, e1, e2, e3; float sum;
    {
      const float t0 = fminf(s[0] * 0.36067376f, 60.f);   // *0.25 * log2(e)
      const float t1 = fminf(s[1] * 0.36067376f, 60.f);
      const float t2 = fminf(s[2] * 0.36067376f, 60.f);
      const float t3 = fminf(s[3] * 0.36067376f, 60.f);
      e0 = (gI * 4 + 0 < kvl) ? exp2f(t0) : 0.f;
      e1 = (gI * 4 + 1 < kvl) ? exp2f(t1) : 0.f;
      e2 = (gI * 4 + 2 < kvl) ? exp2f(t2) : 0.f;
      e3 = (gI * 4 + 3 < kvl) ? exp2f(t3) : 0.f;
      sum = e0 + e1 + e2 + e3;
    }
    sum += __shfl_xor(sum, 16);
    sum += __shfl_xor(sum, 32);
    const float inv = __builtin_amdgcn_rcpf(sum);

    union { bf16x8 v; uint32_t u[4]; } pb;
    pb.u[0] = pk2(e0 * inv, e1 * inv);
    pb.u[1] = pk2(e2 * inv, e3 * inv);
    pb.u[2] = 0; pb.u[3] = 0;

    const int d = h * 16 + q;
    const uint2 vv = *(const uint2*)(vt + swzV(d, cb + gI * 4));
    union { bf16x8 v; uint32_t u[4]; } va;
    va.u[0] = vv.x; va.u[1] = vv.y; va.u[2] = 0; va.u[3] = 0;

    f32x4 o = { 0.f, 0.f, 0.f, 0.f };
    o = __builtin_amdgcn_mfma_f32_16x16x32_bf16(va.v, pb.v, o, 0, 0, 0);

    if (q < 7) {
      *(uint2*)(qb + swzB(qrow0 + q, h * 16 + gI * 4)) =
          make_uint2(pk2(o[0], o[1]), pk2(o[2], o[3]));
    }
  }
}

template <bool WS>
__global__ __attribute__((amdgpu_flat_work_group_size(NT, NT),
                          amdgpu_waves_per_eu(4, 4)))
void pose_kernel(
    const float* __restrict__ feature1, const float* __restrict__ feature2,
    const float* __restrict__ sa1_win, const float* __restrict__ sa1_bin,
    const float* __restrict__ sa1_wout, const float* __restrict__ sa1_bout,
    const float* __restrict__ sa2_win, const float* __restrict__ sa2_bin,
    const float* __restrict__ sa2_wout, const float* __restrict__ sa2_bout,
    const float* __restrict__ ca_win, const float* __restrict__ ca_bin,
    const float* __restrict__ ca_wout, const float* __restrict__ ca_bout,
    const float* __restrict__ ff_w1, const float* __restrict__ ff_b1,
    const float* __restrict__ ff_w2, const float* __restrict__ ff_b2,
    const float* __restrict__ query_embed,
    const float* __restrict__ fc_rot_w, const float* __restrict__ fc_rot_b,
    const float* __restrict__ fc_trans_w, const float* __restrict__ fc_trans_b,
    const short* __restrict__ wbf, float* __restrict__ out)
{
  extern __shared__ char smem[];
  const int t = threadIdx.x;
  const int wid = t >> 6, lane = t & 63;
  const int bi = blockIdx.y;
  const int b0 = blockIdx.x * G;

  // zero-init V buffer (pad slots must be finite for MFMA)
  {
    const uint4 z = { 0, 0, 0, 0 };
    for (int i = t; i < 1024; i += NT) ((uint4*)(smem + OFF_VT))[i] = z;
  }
  // load per-sequence state (coalesced) into swizzled fp32 tiles
  {
    const float* f1p = feature1 + (size_t)b0 * 448;
    const float* f2p = feature2 + (size_t)b0 * 448;
    const float* qe  = query_embed + (size_t)bi * 448;
    const int lim = (BB - b0) * 448;   // guard for the last (partial) block
    for (int idx = t; idx < M1 * 64; idx += NT) {
      const int r = idx >> 6, c = idx & 63;
      const int s = r - div7(r) * 7;
      const bool ok = idx < lim;
      *(float*)(smem + OFF_F1 + swzS(r, c)) = ok ? f1p[idx] : 0.f;
      *(float*)(smem + OFF_F2 + swzS(r, c)) = ok ? f2p[idx] : 0.f;
      *(float*)(smem + OFF_SQ + swzS(r, c)) = qe[s * 64 + c];
    }
  }
  __syncthreads();

  for (int li = 0; li < NL; ++li) {
    const int wo = bi * NL + li;

    // P1: QKV for f1 and f2 (disjoint outputs, one barrier).
    // sched_barrier(0) between the two independent gemms caps the
    // scheduler's cross-gemm liveness fusion (register-pressure control).
    gemm<4, 49, 12, 2, 2, 4, 8, BS_F1, OM_QKV0, 0, 128, 64, WS>(
        smem, wbf + wo * 12288, sa1_win + wo * 12288, sa1_bin + wo * 192, wid, lane);
    __builtin_amdgcn_sched_barrier(0);
    gemm<4, 49, 12, 2, 2, 4, 8, BS_F2, OM_QKV1, 0, 128, 64, WS>(
        smem, wbf + 221184 + wo * 12288, sa2_win + wo * 12288, sa2_bin + wo * 192, wid, lane);
    __syncthreads();

    // P2: attention f1 + f2 (14 units over 8 waves)
    {
      const int u = wid;                       // 0..7
      const int sa = u >= 7, g = u - 7 * sa;
      attn_unit(smem, 49 * sa + 7 * g, 49 * sa + 7 * g, 56 * sa + 8 * g, 7, lane);
      const int u2 = wid + 8;                  // 8..15
      if (u2 < 14) {
        const int g2 = u2 - 7;
        attn_unit(smem, 49 + 7 * g2, 49 + 7 * g2, 56 + 8 * g2, 7, lane);
      }
    }
    __syncthreads();

    // P3: out-proj f1 + f2 (residual RMW)
    gemm<4, 49, 4, 2, 2, 4, 99, BS_QB0, OM_RESF0, 0, 0, 64, WS>(
        smem, wbf + 663552 + wo * 4096, sa1_wout + wo * 4096, sa1_bout + wo * 64, wid, lane);
    __builtin_amdgcn_sched_barrier(0);
    gemm<4, 49, 4, 2, 2, 4, 99, BS_QB49, OM_RESF1, 0, 0, 64, WS>(
        smem, wbf + 737280 + wo * 4096, sa2_wout + wo * 4096, sa2_bout + wo * 64, wid, lane);
    __syncthreads();

    // P4: CA q-proj + merged kv-proj (f1,f2 share ca weights)
    gemm<4, 49, 4, 2, 2, 4, 99, BS_SQ, OM_QCA, 0, 0, 64, WS>(
        smem, wbf + 442368 + wo * 12288, ca_win + wo * 12288, ca_bin + wo * 192, wid, lane);
    __builtin_amdgcn_sched_barrier(0);
    gemm<7, 98, 8, 2, 2, 4, 4, BS_F1F2, OM_KVCA, 64, 128, 64, WS>(
        smem, wbf + 442368 + wo * 12288 + 4096, ca_win + wo * 12288 + 4096,
        ca_bin + wo * 192, wid, lane);
    __syncthreads();

    // P5: attention CA (7 units)
    if (wid < 7)
      attn_unit(smem, 7 * wid, 14 * wid, 16 * wid, 14, lane);
    __syncthreads();

    // P6: CA out-proj (RMW sQ)
    gemm<4, 49, 4, 2, 2, 4, 99, BS_QB0, OM_RESQ, 0, 0, 64, WS>(
        smem, wbf + 811008 + wo * 4096, ca_wout + wo * 4096, ca_bout + wo * 64, wid, lane);
    __syncthreads();

    // P7: FFN-1 (relu -> qb cols 0..31)
    gemm<4, 49, 2, 2, 4, 2, 99, BS_SQ, OM_RELU, 0, 0, 64, WS>(
        smem, wbf + 884736 + wo * 2048, ff_w1 + wo * 2048, ff_b1 + wo * 32, wid, lane);
    __syncthreads();

    // P8: FFN-2 (RMW sQ)
    gemm<4, 49, 4, 1, 2, 4, 99, BS_QB0, OM_RESQ, 0, 0, 32, WS>(
        smem, wbf + 921600 + wo * 2048, ff_w2 + wo * 2048, ff_b2 + wo * 64, wid, lane);
    __syncthreads();
  }

  // ---------- pose head ----------
  float* cs = (float*)(smem + OFF_QB);   // [7][64] fp32 scratch
  if (t < G * 64) {
    const int g = t >> 6, c = t & 63;
    float a = 0.f;
#pragma unroll
    for (int s = 0; s < 7; ++s) a += *(const float*)(smem + OFF_SQ + swzS(g * 7 + s, c));
    cs[t] = a;
  }
  __syncthreads();
  const int ncols = bi ? 3 : 4;
  if (t < G * ncols) {
    const int g = t / ncols, cc = t - g * ncols;
    if (b0 + g < BB) {
      const float* wv = bi ? (fc_trans_w + cc * 64) : (fc_rot_w + cc * 64);
      float acc = 0.f;
#pragma unroll
      for (int k = 0; k < 64; ++k) acc += cs[g * 64 + k] * wv[k];
      const float bb = bi ? fc_trans_b[cc] : fc_rot_b[cc];
      out[(size_t)(b0 + g) * 7 + (bi ? 4 : 0) + cc] = acc * (1.f / 7.f) + bb;
    }
  }
}

// Convert all weight matrices fp32 -> bf16 into workspace (once per call).
__global__ void prep_kernel(const float* __restrict__ a0, const float* __restrict__ a1,
                            const float* __restrict__ a2, const float* __restrict__ a3,
                            const float* __restrict__ a4, const float* __restrict__ a5,
                            const float* __restrict__ a6, const float* __restrict__ a7,
                            short* __restrict__ dst)
{
  for (int i = blockIdx.x * blockDim.x + threadIdx.x; i < 958464;
       i += gridDim.x * blockDim.x) {
    const float* s; int j;
    if      (i < 221184) { s = a0; j = i; }
    else if (i < 442368) { s = a1; j = i - 221184; }
    else if (i < 663552) { s = a2; j = i - 442368; }
    else if (i < 737280) { s = a3; j = i - 663552; }
    else if (i < 811008) { s = a4; j = i - 737280; }
    else if (i < 884736) { s = a5; j = i - 811008; }
    else if (i < 921600) { s = a6; j = i - 884736; }
    else                 { s = a7; j = i - 921600; }
    dst[i] = (short)f2bf(s[j]);
  }
}

} // namespace

extern "C" void kernel_launch(void* const* d_in, const int* in_sizes, int n_in,
                              void* d_out, int out_size, void* d_ws, size_t ws_size,
                              hipStream_t stream)
{
  const float* feature1    = (const float*)d_in[0];
  const float* feature2    = (const float*)d_in[1];
  const float* sa1_win     = (const float*)d_in[2];
  const float* sa1_bin     = (const float*)d_in[3];
  const float* sa1_wout    = (const float*)d_in[4];
  const float* sa1_bout    = (const float*)d_in[5];
  const float* sa2_win     = (const float*)d_in[6];
  const float* sa2_bin     = (const float*)d_in[7];
  const float* sa2_wout    = (const float*)d_in[8];
  const float* sa2_bout    = (const float*)d_in[9];
  const float* ca_win      = (const float*)d_in[10];
  const float* ca_bin      = (const float*)d_in[11];
  const float* ca_wout     = (const float*)d_in[12];
  const float* ca_bout     = (const float*)d_in[13];
  const float* ff_w1       = (const float*)d_in[14];
  const float* ff_b1       = (const float*)d_in[15];
  const float* ff_w2       = (const float*)d_in[16];
  const float* ff_b2       = (const float*)d_in[17];
  const float* query_embed = (const float*)d_in[18];
  const float* fc_rot_w    = (const float*)d_in[19];
  const float* fc_rot_b    = (const float*)d_in[20];
  const float* fc_trans_w  = (const float*)d_in[21];
  const float* fc_trans_b  = (const float*)d_in[22];

  const bool ws_ok = (d_ws != nullptr) && (ws_size >= (size_t)958464 * 2);
  dim3 grid((BB + G - 1) / G, 2);

  if (ws_ok) {
    prep_kernel<<<dim3(936), 512, 0, stream>>>(sa1_win, sa2_win, ca_win,
                                               sa1_wout, sa2_wout, ca_wout,
                                               ff_w1, ff_w2, (short*)d_ws);
    hipFuncSetAttribute(reinterpret_cast<const void*>(&pose_kernel<true>),
                        hipFuncAttributeMaxDynamicSharedMemorySize, SMEM_TOTAL);
    pose_kernel<true><<<grid, NT, SMEM_TOTAL, stream>>>(
        feature1, feature2,
        sa1_win, sa1_bin, sa1_wout, sa1_bout,
        sa2_win, sa2_bin, sa2_wout, sa2_bout,
        ca_win, ca_bin, ca_wout, ca_bout,
        ff_w1, ff_b1, ff_w2, ff_b2,
        query_embed, fc_rot_w, fc_rot_b, fc_trans_w, fc_trans_b,
        (const short*)d_ws, (float*)d_out);
  } else {
    hipFuncSetAttribute(reinterpret_cast<const void*>(&pose_kernel<false>),
                        hipFuncAttributeMaxDynamicSharedMemorySize, SMEM_TOTAL);
    pose_kernel<false><<<grid, NT, SMEM_TOTAL, stream>>>(
        feature1, feature2,
        sa1_win, sa1_bin, sa1_wout, sa1_bout,
        sa2_win, sa2_bin, sa2_wout, sa2_bout,
        ca_win, ca_bin, ca_wout, ca_bout,
        ff_w1, ff_b1, ff_w2, ff_b2,
        query_embed, fc_rot_w, fc_rot_b, fc_trans_w, fc_trans_b,
        (const short*)d_ws, (float*)d_out);
  }
}

// Round 8
// 1494.055 us; speedup vs baseline: 1.4882x; 1.4740x over previous
//
#include <hip/hip_runtime.h>
#include <hip/hip_bf16.h>

namespace {

using bf16x8 = __attribute__((ext_vector_type(8))) short;
using f32x4  = __attribute__((ext_vector_type(4))) float;

constexpr int NL = 9, S = 7, BB = 8192;
constexpr int G = 4;            // sequences per block (1 per wave in attn)
constexpr int M = G * S;        // 28 token rows
constexpr int NT = 256;         // 4 waves

// LDS layout (bytes)
constexpr int OFF_F1 = 0;       // fp32 [28][64] swizzled (32B granule)
constexpr int OFF_F2 = 7168;
constexpr int OFF_Q  = 14336;
constexpr int OFF_QB = 21504;   // bf16 [28][64] swizzled (Q / ctx / ffn-hidden)
constexpr int OFF_KB = 25088;   // bf16 [56][64] swizzled (K; CA uses 56 rows)
constexpr int OFF_VT = 32256;   // bf16 V [64 d][64 kv] swizzled
constexpr int SMEM_TOTAL = 40448;   // x4 = 161792 <= 163840 -> 4 blocks/CU

__device__ __forceinline__ unsigned short f2bf(float f) {
  union { __hip_bfloat16 h; unsigned short s; } u;
  u.h = __float2bfloat16(f);
  return u.s;
}
__device__ __forceinline__ uint32_t pk2(float a, float b) {
  return (uint32_t)f2bf(a) | ((uint32_t)f2bf(b) << 16);
}
__device__ __forceinline__ int swzS(int r, int c) {   // fp32 [*][64]
  return r * 256 + ((((c >> 3) ^ (r & 7)) << 5) | ((c & 7) << 2));
}
__device__ __forceinline__ int swzB(int r, int c) {   // bf16 [*][64]
  return r * 128 + ((((c >> 3) ^ (r & 7)) << 4) | ((c & 7) << 1));
}
__device__ __forceinline__ int swzV(int d, int kv) {  // bf16 [64][64]
  return d * 128 + ((((kv >> 3) ^ (d & 7)) << 4) | ((kv & 7) << 1));
}
__device__ __forceinline__ int div7(int t) { return (t * 9363) >> 16; }  // t < 56

// state fp32 (swizzled) -> bf16x8 fragment: 8 consecutive k (k0 % 8 == 0)
__device__ __forceinline__ bf16x8 ldStateFrag(const char* base, int r, int k0) {
  const float4* p = (const float4*)(base + r * 256 + (((k0 >> 3) ^ (r & 7)) << 5));
  float4 x = p[0], y = p[1];
  union { bf16x8 v; uint32_t u[4]; } o;
  o.u[0] = pk2(x.x, x.y); o.u[1] = pk2(x.z, x.w);
  o.u[2] = pk2(y.x, y.y); o.u[3] = pk2(y.z, y.w);
  return o.v;
}
__device__ __forceinline__ bf16x8 ldBfFrag(const char* base, int r, int k0) {
  return *(const bf16x8*)(base + r * 128 + (((k0 >> 3) ^ (r & 7)) << 4));
}

// Swapped-operand GEMM (round-3 proven structure, re-parameterized for 4 waves).
// Normal tiles (nt < VNT): D = W x state^T (lane: token col, 4 consecutive
// feature rows -> packed 8B stores; bias float4 into acc).
// V tiles (nt >= VNT): D = state x W^T (lane: feature col, 4 token rows).
template <int MTOT, int NTOT, int KF, int WMG, int WNG, int VNT, bool WS,
          class BLD, class STN, class STV>
__device__ __forceinline__ void gemm_sw(const short* __restrict__ wbf,
                                        const float* __restrict__ wf,
                                        const float* __restrict__ bias,
                                        int ldK, int wid, int lane,
                                        BLD bld, STN stn, STV stv)
{
  const int wm = wid / WNG, wn = wid % WNG;
  const int q = lane & 15, gI = lane >> 4;
  constexpr int MPW = (MTOT + WMG - 1) / WMG;
  constexpr int NPW = NTOT / WNG;
  bf16x8 bfr[MPW][KF];
#pragma unroll
  for (int i = 0; i < MPW; ++i) {
    const int mt = wm * MPW + i;
    if (mt < MTOT) {
#pragma unroll
      for (int kf = 0; kf < KF; ++kf)
        bfr[i][kf] = bld(mt * 16 + q, kf * 32 + gI * 8);
    }
  }
#pragma unroll
  for (int j = 0; j < NPW; ++j) {
    const int nt = wn * NPW + j;
    bf16x8 afr[KF];
#pragma unroll
    for (int kf = 0; kf < KF; ++kf) {
      const int k0 = kf * 32 + gI * 8;
      if constexpr (WS) {
        afr[kf] = *(const bf16x8*)(wbf + (size_t)(nt * 16 + q) * ldK + k0);
      } else {
        const float* wp = wf + (size_t)(nt * 16 + q) * ldK + k0;
        float4 x = *(const float4*)wp, y = *(const float4*)(wp + 4);
        union { bf16x8 v; uint32_t u[4]; } o;
        o.u[0] = pk2(x.x, x.y); o.u[1] = pk2(x.z, x.w);
        o.u[2] = pk2(y.x, y.y); o.u[3] = pk2(y.z, y.w);
        afr[kf] = o.v;
      }
    }
    if (nt < VNT) {
      const float4 b4 = *(const float4*)(bias + nt * 16 + gI * 4);
#pragma unroll
      for (int i = 0; i < MPW; ++i) {
        const int mt = wm * MPW + i;
        if (mt < MTOT) {
          f32x4 acc = { b4.x, b4.y, b4.z, b4.w };
#pragma unroll
          for (int kf = 0; kf < KF; ++kf)
            acc = __builtin_amdgcn_mfma_f32_16x16x32_bf16(afr[kf], bfr[i][kf], acc, 0, 0, 0);
          stn(mt, nt, acc);
        }
      }
    } else {
      const float bv = bias[nt * 16 + q];
#pragma unroll
      for (int i = 0; i < MPW; ++i) {
        const int mt = wm * MPW + i;
        if (mt < MTOT) {
          f32x4 acc = { bv, bv, bv, bv };
#pragma unroll
          for (int kf = 0; kf < KF; ++kf)
            acc = __builtin_amdgcn_mfma_f32_16x16x32_bf16(bfr[i][kf], afr[kf], acc, 0, 0, 0);
          stv(mt, nt, acc);
        }
      }
    }
  }
}

// Attention: wave wid owns sequence g = wid, loops over 4 heads.
template <bool CA_>
__device__ __forceinline__ void attn(char* qb, const char* kb, const char* vt,
                                     int wid, int lane)
{
  const int q = lane & 15, gI = lane >> 4;
  const int g = wid;
  constexpr int KVL = CA_ ? 14 : 7;
#pragma unroll
  for (int h = 0; h < 4; ++h) {
    bf16x8 kfrag = {}, qfrag = {};
    if (gI < 2) {
      int qrow = g * 7 + q; qrow = qrow > 27 ? 27 : qrow;
      qfrag = ldBfFrag(qb, qrow, h * 16 + gI * 8);
      int kvr;
      if constexpr (CA_) {
        kvr = (q < 7) ? (g * 7 + q) : (21 + g * 7 + q);   // f2 rows at 28+
        kvr = kvr > 55 ? 55 : kvr;
      } else {
        kvr = g * 7 + q; kvr = kvr > 27 ? 27 : kvr;
      }
      kfrag = ldBfFrag(kb, kvr, h * 16 + gI * 8);
    }
    f32x4 s = { 0.f, 0.f, 0.f, 0.f };
    s = __builtin_amdgcn_mfma_f32_16x16x32_bf16(kfrag, qfrag, s, 0, 0, 0);

    float e[4]; float sum = 0.f;
#pragma unroll
    for (int jj = 0; jj < 4; ++jj) {
      const int kvloc = gI * 4 + jj;
      const float tt = fminf(s[jj] * 0.36067376f, 60.f);   // *0.25 * log2(e)
      e[jj] = (kvloc < KVL) ? exp2f(tt) : 0.f;
      sum += e[jj];
    }
    sum += __shfl_xor(sum, 16);
    sum += __shfl_xor(sum, 32);
    const float inv = __builtin_amdgcn_rcpf(sum);

    union { bf16x8 v; uint32_t u[4]; } pb;
    pb.u[0] = pk2(e[0] * inv, e[1] * inv);
    pb.u[1] = pk2(e[2] * inv, e[3] * inv);
    pb.u[2] = 0; pb.u[3] = 0;

    const int d = h * 16 + q;
    const int kv0 = (CA_ ? g * 16 : g * 8) + gI * 4;
    const uint2 vv = *(const uint2*)(vt + swzV(d, kv0));
    union { bf16x8 v; uint32_t u[4]; } va;
    va.u[0] = vv.x; va.u[1] = vv.y; va.u[2] = 0; va.u[3] = 0;

    f32x4 o = { 0.f, 0.f, 0.f, 0.f };
    o = __builtin_amdgcn_mfma_f32_16x16x32_bf16(va.v, pb.v, o, 0, 0, 0);

    if (q < 7) {
      const int tok = g * 7 + q, c0 = h * 16 + gI * 4;
      *(uint2*)(qb + swzB(tok, c0)) = make_uint2(pk2(o[0], o[1]), pk2(o[2], o[3]));
    }
  }
}

template <bool WS>
__global__ __launch_bounds__(NT, 4) void pose_kernel(
    const float* __restrict__ feature1, const float* __restrict__ feature2,
    const float* __restrict__ sa1_win, const float* __restrict__ sa1_bin,
    const float* __restrict__ sa1_wout, const float* __restrict__ sa1_bout,
    const float* __restrict__ sa2_win, const float* __restrict__ sa2_bin,
    const float* __restrict__ sa2_wout, const float* __restrict__ sa2_bout,
    const float* __restrict__ ca_win, const float* __restrict__ ca_bin,
    const float* __restrict__ ca_wout, const float* __restrict__ ca_bout,
    const float* __restrict__ ff_w1, const float* __restrict__ ff_b1,
    const float* __restrict__ ff_w2, const float* __restrict__ ff_b2,
    const float* __restrict__ query_embed,
    const float* __restrict__ fc_rot_w, const float* __restrict__ fc_rot_b,
    const float* __restrict__ fc_trans_w, const float* __restrict__ fc_trans_b,
    const short* __restrict__ wbf, float* __restrict__ out)
{
  extern __shared__ char smem[];
  char* sF1 = smem + OFF_F1;
  char* sF2 = smem + OFF_F2;
  char* sQ  = smem + OFF_Q;
  char* qb  = smem + OFF_QB;
  char* kb  = smem + OFF_KB;
  char* vt  = smem + OFF_VT;

  const int t = threadIdx.x;
  const int wid = t >> 6, lane = t & 63;
  const int q = lane & 15, gI = lane >> 4;
  const int bi = blockIdx.y;
  const int b0 = blockIdx.x * G;

  // zero-init V buffer once (pad slots must be finite: NaN*0 = NaN in MFMA)
  {
    const uint4 z = { 0, 0, 0, 0 };
    for (int i = t; i < 512; i += NT) ((uint4*)vt)[i] = z;
  }
  // load per-sequence state (coalesced) into swizzled fp32 tiles
  {
    const float* f1p = feature1 + (size_t)b0 * (S * 64);
    const float* f2p = feature2 + (size_t)b0 * (S * 64);
    const float* qe  = query_embed + (size_t)bi * (S * 64);
    for (int idx = t; idx < M * 64; idx += NT) {
      const int r = idx >> 6, c = idx & 63;
      const int s = r - div7(r) * 7;
      *(float*)(sF1 + swzS(r, c)) = f1p[idx];
      *(float*)(sF2 + swzS(r, c)) = f2p[idx];
      *(float*)(sQ + swzS(r, c))  = qe[s * 64 + c];
    }
  }
  __syncthreads();

  const auto stv_none = [](int, int, f32x4) {};

  for (int li = 0; li < NL; ++li) {
    const int wo = bi * NL + li;
    const short* W_in[3]  = { wbf + 0      + wo * 12288,
                              wbf + 221184 + wo * 12288,
                              wbf + 442368 + wo * 12288 };
    const short* W_out[3] = { wbf + 663552 + wo * 4096,
                              wbf + 737280 + wo * 4096,
                              wbf + 811008 + wo * 4096 };
    const short* W_f1 = wbf + 884736 + wo * 2048;
    const short* W_f2 = wbf + 921600 + wo * 2048;
    const float* F_in[3]  = { sa1_win + wo * 12288, sa2_win + wo * 12288, ca_win + wo * 12288 };
    const float* F_out[3] = { sa1_wout + wo * 4096, sa2_wout + wo * 4096, ca_wout + wo * 4096 };
    const float* B_in[3]  = { sa1_bin + wo * 192, sa2_bin + wo * 192, ca_bin + wo * 192 };
    const float* B_out[3] = { sa1_bout + wo * 64, sa2_bout + wo * 64, ca_bout + wo * 64 };

    // ---------- self-attention on f1, then f2 ----------
    for (int sa = 0; sa < 2; ++sa) {
      char* ST = sa ? sF2 : sF1;
      auto bld = [&](int r, int k0) { return ldStateFrag(ST, r > 27 ? 27 : r, k0); };
      auto stn = [&](int mt, int nt, f32x4 a) {        // nt<4: Q, 4..7: K
        const int tok = mt * 16 + q; if (tok >= M) return;
        if (nt < 4) {
          *(uint2*)(qb + swzB(tok, nt * 16 + gI * 4)) =
              make_uint2(pk2(a[0], a[1]), pk2(a[2], a[3]));
        } else {
          *(uint2*)(kb + swzB(tok, (nt - 4) * 16 + gI * 4)) =
              make_uint2(pk2(a[0], a[1]), pk2(a[2], a[3]));
        }
      };
      auto stv = [&](int mt, int nt, f32x4 a) {        // nt>=8: V -> vt[d][kv]
        const int d = (nt - 8) * 16 + q;
#pragma unroll
        for (int jj = 0; jj < 4; ++jj) {
          const int tok = mt * 16 + gI * 4 + jj;
          if (tok < M) {
            const int g = div7(tok);
            *(short*)(vt + swzV(d, g * 8 + (tok - g * 7))) = (short)f2bf(a[jj]);
          }
        }
      };
      gemm_sw<2, 12, 2, 2, 2, 8, WS>(W_in[sa], F_in[sa], B_in[sa], 64, wid, lane, bld, stn, stv);
      __syncthreads();
      attn<false>(qb, kb, vt, wid, lane);
      __syncthreads();
      auto bldc = [&](int r, int k0) { return ldBfFrag(qb, r > 27 ? 27 : r, k0); };
      auto stres = [&](int mt, int nt, f32x4 a) {
        const int tok = mt * 16 + q; if (tok >= M) return;
        const int c0 = nt * 16 + gI * 4;
        float4* p = (float4*)(ST + tok * 256 + (((c0 >> 3) ^ (tok & 7)) << 5) + (c0 & 7) * 4);
        float4 v = *p;
        v.x += a[0]; v.y += a[1]; v.z += a[2]; v.w += a[3];
        *p = v;
      };
      gemm_sw<2, 4, 2, 2, 2, 4, WS>(W_out[sa], F_out[sa], B_out[sa], 64, wid, lane, bldc, stres, stv_none);
      __syncthreads();
    }

    // ---------- cross-attention ----------
    {
      auto bldq = [&](int r, int k0) { return ldStateFrag(sQ, r > 27 ? 27 : r, k0); };
      auto stq = [&](int mt, int nt, f32x4 a) {
        const int tok = mt * 16 + q; if (tok >= M) return;
        *(uint2*)(qb + swzB(tok, nt * 16 + gI * 4)) =
            make_uint2(pk2(a[0], a[1]), pk2(a[2], a[3]));
      };
      gemm_sw<2, 4, 2, 2, 2, 4, WS>(W_in[2], F_in[2], B_in[2], 64, wid, lane, bldq, stq, stv_none);

      for (int src = 0; src < 2; ++src) {
        const char* SRC = src ? sF2 : sF1;
        auto bld = [&](int r, int k0) { return ldStateFrag(SRC, r > 27 ? 27 : r, k0); };
        auto stk = [&](int mt, int nt, f32x4 a) {      // nt<4: K
          const int tok = mt * 16 + q; if (tok >= M) return;
          *(uint2*)(kb + swzB(tok + src * 28, nt * 16 + gI * 4)) =
              make_uint2(pk2(a[0], a[1]), pk2(a[2], a[3]));
        };
        auto stv = [&](int mt, int nt, f32x4 a) {      // nt>=4: V
          const int d = (nt - 4) * 16 + q;
#pragma unroll
          for (int jj = 0; jj < 4; ++jj) {
            const int tok = mt * 16 + gI * 4 + jj;
            if (tok < M) {
              const int g = div7(tok);
              *(short*)(vt + swzV(d, g * 16 + (tok - g * 7) + src * 7)) = (short)f2bf(a[jj]);
            }
          }
        };
        gemm_sw<2, 8, 2, 2, 2, 4, WS>(W_in[2] + 4096, F_in[2] + 4096, B_in[2] + 64,
                                      64, wid, lane, bld, stk, stv);
      }
      __syncthreads();
      attn<true>(qb, kb, vt, wid, lane);
      __syncthreads();
      auto bldc = [&](int r, int k0) { return ldBfFrag(qb, r > 27 ? 27 : r, k0); };
      auto stres = [&](int mt, int nt, f32x4 a) {
        const int tok = mt * 16 + q; if (tok >= M) return;
        const int c0 = nt * 16 + gI * 4;
        float4* p = (float4*)(sQ + tok * 256 + (((c0 >> 3) ^ (tok & 7)) << 5) + (c0 & 7) * 4);
        float4 v = *p;
        v.x += a[0]; v.y += a[1]; v.z += a[2]; v.w += a[3];
        *p = v;
      };
      gemm_sw<2, 4, 2, 2, 2, 4, WS>(W_out[2], F_out[2], B_out[2], 64, wid, lane, bldc, stres, stv_none);
      __syncthreads();
    }

    // ---------- FFN ----------
    {
      auto bldq = [&](int r, int k0) { return ldStateFrag(sQ, r > 27 ? 27 : r, k0); };
      auto sth = [&](int mt, int nt, f32x4 a) {        // relu -> qb cols 0..31
        const int tok = mt * 16 + q; if (tok >= M) return;
        *(uint2*)(qb + swzB(tok, nt * 16 + gI * 4)) =
            make_uint2(pk2(fmaxf(a[0], 0.f), fmaxf(a[1], 0.f)),
                       pk2(fmaxf(a[2], 0.f), fmaxf(a[3], 0.f)));
      };
      gemm_sw<2, 2, 2, 2, 2, 2, WS>(W_f1, ff_w1 + wo * 2048, ff_b1 + wo * 32,
                                    64, wid, lane, bldq, sth, stv_none);
      __syncthreads();
      auto bldh = [&](int r, int k0) { return ldBfFrag(qb, r > 27 ? 27 : r, k0); };
      auto stres = [&](int mt, int nt, f32x4 a) {
        const int tok = mt * 16 + q; if (tok >= M) return;
        const int c0 = nt * 16 + gI * 4;
        float4* p = (float4*)(sQ + tok * 256 + (((c0 >> 3) ^ (tok & 7)) << 5) + (c0 & 7) * 4);
        float4 v = *p;
        v.x += a[0]; v.y += a[1]; v.z += a[2]; v.w += a[3];
        *p = v;
      };
      gemm_sw<2, 4, 1, 2, 2, 4, WS>(W_f2, ff_w2 + wo * 2048, ff_b2 + wo * 64,
                                    32, wid, lane, bldh, stres, stv_none);
      __syncthreads();
    }
  }

  // ---------- pose head ----------
  float* cs = (float*)qb;   // [4][64] fp32 scratch (qb is free now)
  {
    const int g = t >> 6, c = t & 63;   // 256 threads == 4*64 items
    float a = 0.f;
#pragma unroll
    for (int s = 0; s < 7; ++s) a += *(const float*)(sQ + swzS(g * 7 + s, c));
    cs[t] = a;
  }
  __syncthreads();
  const int ncols = bi ? 3 : 4;
  if (t < G * ncols) {
    const int g = t / ncols, cc = t - g * ncols;
    const float* wv = bi ? (fc_trans_w + cc * 64) : (fc_rot_w + cc * 64);
    float acc = 0.f;
#pragma unroll
    for (int k = 0; k < 64; ++k) acc += cs[g * 64 + k] * wv[k];
    const float bb = bi ? fc_trans_b[cc] : fc_rot_b[cc];
    out[(size_t)(b0 + g) * 7 + (bi ? 4 : 0) + cc] = acc * (1.f / 7.f) + bb;
  }
}

// Convert all weight matrices fp32 -> bf16 into workspace (once per call).
__global__ void prep_kernel(const float* __restrict__ a0, const float* __restrict__ a1,
                            const float* __restrict__ a2, const float* __restrict__ a3,
                            const float* __restrict__ a4, const float* __restrict__ a5,
                            const float* __restrict__ a6, const float* __restrict__ a7,
                            short* __restrict__ dst)
{
  for (int i = blockIdx.x * blockDim.x + threadIdx.x; i < 958464;
       i += gridDim.x * blockDim.x) {
    const float* s; int j;
    if      (i < 221184) { s = a0; j = i; }
    else if (i < 442368) { s = a1; j = i - 221184; }
    else if (i < 663552) { s = a2; j = i - 442368; }
    else if (i < 737280) { s = a3; j = i - 663552; }
    else if (i < 811008) { s = a4; j = i - 737280; }
    else if (i < 884736) { s = a5; j = i - 811008; }
    else if (i < 921600) { s = a6; j = i - 884736; }
    else                 { s = a7; j = i - 921600; }
    dst[i] = (short)f2bf(s[j]);
  }
}

} // namespace

extern "C" void kernel_launch(void* const* d_in, const int* in_sizes, int n_in,
                              void* d_out, int out_size, void* d_ws, size_t ws_size,
                              hipStream_t stream)
{
  const float* feature1    = (const float*)d_in[0];
  const float* feature2    = (const float*)d_in[1];
  const float* sa1_win     = (const float*)d_in[2];
  const float* sa1_bin     = (const float*)d_in[3];
  const float* sa1_wout    = (const float*)d_in[4];
  const float* sa1_bout    = (const float*)d_in[5];
  const float* sa2_win     = (const float*)d_in[6];
  const float* sa2_bin     = (const float*)d_in[7];
  const float* sa2_wout    = (const float*)d_in[8];
  const float* sa2_bout    = (const float*)d_in[9];
  const float* ca_win      = (const float*)d_in[10];
  const float* ca_bin      = (const float*)d_in[11];
  const float* ca_wout     = (const float*)d_in[12];
  const float* ca_bout     = (const float*)d_in[13];
  const float* ff_w1       = (const float*)d_in[14];
  const float* ff_b1       = (const float*)d_in[15];
  const float* ff_w2       = (const float*)d_in[16];
  const float* ff_b2       = (const float*)d_in[17];
  const float* query_embed = (const float*)d_in[18];
  const float* fc_rot_w    = (const float*)d_in[19];
  const float* fc_rot_b    = (const float*)d_in[20];
  const float* fc_trans_w  = (const float*)d_in[21];
  const float* fc_trans_b  = (const float*)d_in[22];

  const bool ws_ok = (d_ws != nullptr) && (ws_size >= (size_t)958464 * 2);
  dim3 grid(BB / G, 2);

  if (ws_ok) {
    prep_kernel<<<dim3(936), 512, 0, stream>>>(sa1_win, sa2_win, ca_win,
                                               sa1_wout, sa2_wout, ca_wout,
                                               ff_w1, ff_w2, (short*)d_ws);
    hipFuncSetAttribute(reinterpret_cast<const void*>(&pose_kernel<true>),
                        hipFuncAttributeMaxDynamicSharedMemorySize, SMEM_TOTAL);
    pose_kernel<true><<<grid, NT, SMEM_TOTAL, stream>>>(
        feature1, feature2,
        sa1_win, sa1_bin, sa1_wout, sa1_bout,
        sa2_win, sa2_bin, sa2_wout, sa2_bout,
        ca_win, ca_bin, ca_wout, ca_bout,
        ff_w1, ff_b1, ff_w2, ff_b2,
        query_embed, fc_rot_w, fc_rot_b, fc_trans_w, fc_trans_b,
        (const short*)d_ws, (float*)d_out);
  } else {
    hipFuncSetAttribute(reinterpret_cast<const void*>(&pose_kernel<false>),
                        hipFuncAttributeMaxDynamicSharedMemorySize, SMEM_TOTAL);
    pose_kernel<false><<<grid, NT, SMEM_TOTAL, stream>>>(
        feature1, feature2,
        sa1_win, sa1_bin, sa1_wout, sa1_bout,
        sa2_win, sa2_bin, sa2_wout, sa2_bout,
        ca_win, ca_bin, ca_wout, ca_bout,
        ff_w1, ff_b1, ff_w2, ff_b2,
        query_embed, fc_rot_w, fc_rot_b, fc_trans_w, fc_trans_b,
        (const short*)d_ws, (float*)d_out);
  }
}